// Round 5
// baseline (2132.867 us; speedup 1.0000x reference)
//
#include <hip/hip_runtime.h>

typedef short short8 __attribute__((ext_vector_type(8)));
typedef float f32x4 __attribute__((ext_vector_type(4)));
typedef unsigned short u16;

static constexpr int BATCH = 2, S = 2048, H = 4096, NHEAD = 32, HDIM = 128;

__device__ __forceinline__ u16 f2b(float f) {
  union { float f; unsigned u; } v; v.f = f;
  return (u16)((v.u + 0x7fffu + ((v.u >> 16) & 1u)) >> 16);
}
__device__ __forceinline__ float b2f(u16 h) {
  union { unsigned u; float f; } v; v.u = ((unsigned)h) << 16;
  return v.f;
}

__device__ __forceinline__ void gl16(const u16* g, u16* l) {
  __builtin_amdgcn_global_load_lds((__attribute__((address_space(1))) void*)g,
                                   (__attribute__((address_space(3))) void*)l,
                                   16, 0, 0);
}

#define MFMA(acc, a, b) \
  acc = __builtin_amdgcn_mfma_f32_16x16x32_bf16(a, b, acc, 0, 0, 0)

// ---- f32 -> bf16 convert, 4 elems/thread, exact grid ----
__global__ __launch_bounds__(256) void cvt_bf16(const float* __restrict__ in,
                                                u16* __restrict__ out) {
  size_t i = ((size_t)blockIdx.x * 256 + threadIdx.x) * 4;
  float4 v = *(const float4*)(in + i);
  ushort4 o = { f2b(v.x), f2b(v.y), f2b(v.z), f2b(v.w) };
  *(ushort4*)(out + i) = o;
}

// ---- NT GEMM: C[M][N] = A[M][K] * B[N][K]^T (both K-contiguous bf16) ----
template <bool F32OUT>
__global__ __launch_bounds__(256) void gemm_bt(const u16* __restrict__ A,
                                               const u16* __restrict__ B,
                                               void* __restrict__ C,
                                               int M, int N, int K) {
  __shared__ u16 As[128 * 32];
  __shared__ u16 Bs[128 * 32];
  const int nbn = N >> 7;
  const int bm = blockIdx.x / nbn, bn = blockIdx.x % nbn;
  const int tid = threadIdx.x, lane = tid & 63;
  const int w = tid >> 6, wr = w >> 1, wc = w & 1;
  const int hi = lane >> 4, lo = lane & 15;
  f32x4 acc[4][4] = {};
  const u16* Ag = A + (size_t)bm * 128 * K;
  const u16* Bg = B + (size_t)bn * 128 * K;
  const int c0 = tid, c1 = tid + 256;
  const u16* a0 = Ag + (size_t)(c0 >> 2) * K + (c0 & 3) * 8;
  const u16* a1 = Ag + (size_t)(c1 >> 2) * K + (c1 & 3) * 8;
  const u16* b0 = Bg + (size_t)(c0 >> 2) * K + (c0 & 3) * 8;
  const u16* b1 = Bg + (size_t)(c1 >> 2) * K + (c1 & 3) * 8;
  u16* la0 = &As[c0 * 8]; u16* la1 = &As[c1 * 8];
  u16* lb0 = &Bs[c0 * 8]; u16* lb1 = &Bs[c1 * 8];
  for (int kt = 0; kt < K; kt += 32) {
    __syncthreads();
    gl16(a0 + kt, la0); gl16(a1 + kt, la1);
    gl16(b0 + kt, lb0); gl16(b1 + kt, lb1);
    __syncthreads();
    short8 af[4], bf[4];
#pragma unroll
    for (int m = 0; m < 4; ++m)
      af[m] = *(const short8*)&As[(wr * 64 + m * 16 + lo) * 32 + hi * 8];
#pragma unroll
    for (int n = 0; n < 4; ++n)
      bf[n] = *(const short8*)&Bs[(wc * 64 + n * 16 + lo) * 32 + hi * 8];
#pragma unroll
    for (int m = 0; m < 4; ++m)
#pragma unroll
      for (int n = 0; n < 4; ++n)
        acc[m][n] = __builtin_amdgcn_mfma_f32_16x16x32_bf16(af[m], bf[n],
                                                            acc[m][n], 0, 0, 0);
  }
  const int r0 = bm * 128 + wr * 64 + hi * 4;
  const int col0 = bn * 128 + wc * 64 + lo;
#pragma unroll
  for (int m = 0; m < 4; ++m)
#pragma unroll
    for (int n = 0; n < 4; ++n)
#pragma unroll
      for (int j = 0; j < 4; ++j) {
        size_t idx = (size_t)(r0 + m * 16 + j) * N + col0 + n * 16;
        if (F32OUT) ((float*)C)[idx] = acc[m][n][j];
        else        ((u16*)C)[idx]   = f2b(acc[m][n][j]);
      }
}

// ---- RoPE + scatter: qkv[b][s][12288] -> q_r,k_r [b][nh][s][hd] ----
__global__ __launch_bounds__(256) void rope_qk(const u16* __restrict__ qkv,
                                               const int* __restrict__ pos,
                                               u16* __restrict__ qr,
                                               u16* __restrict__ kr) {
  __shared__ float cs[64], sn[64];
  const int bs = blockIdx.x;
  const int b = bs >> 11, s = bs & 2047;
  const int tid = threadIdx.x;
  if (tid < 64) {
    float p = (float)pos[bs];
    float freq = __powf(10000.0f, -(float)tid * (1.0f / 64.0f));
    float a = p * freq;
    sn[tid] = sinf(a);
    cs[tid] = cosf(a);
  }
  __syncthreads();
  const u16* src = qkv + (size_t)bs * 12288;
  for (int i = tid; i < 4096; i += 256) {
    int nh = i >> 7, hd = i & 127, f = hd & 63;
    float c = cs[f], sv = sn[f];
    int oth = (hd < 64) ? i + 64 : i - 64;
    size_t dst = ((size_t)(b * NHEAD + nh) * S + s) * HDIM + hd;
    float x = b2f(src[i]), xo = b2f(src[oth]);
    qr[dst] = f2b((hd < 64) ? (x * c - xo * sv) : (x * c + xo * sv));
    float xk = b2f(src[4096 + i]), xko = b2f(src[4096 + oth]);
    kr[dst] = f2b((hd < 64) ? (xk * c - xko * sv) : (xk * c + xko * sv));
  }
}

// ---- flash attention fwd, causal. 1 block = (b, h, 64 q-rows), 4 waves x 16 rows.
// Ks: XOR-swizzled [64 kv][128 d] (granule ^ (row&7)).
// Vt: V transposed [128 d][64 kv], kv-granule swizzled by g(d)=((d>>3)^d)&7.
// Staging registers are NAMED (k0..k3, v0..v3) with pure-ALU u16 extraction —
// no address-taken arrays (round-4's 550 MB scratch-spill lesson).
// Ps: per-wave XOR-swizzled [16][64].
__global__ __launch_bounds__(256, 3) void flash_fwd(const u16* __restrict__ q,
                                                    const u16* __restrict__ k,
                                                    const u16* __restrict__ qkv,
                                                    u16* __restrict__ o) {
  __shared__ u16 Ks[64 * 128];
  __shared__ u16 Vt[128 * 64];
  __shared__ u16 Ps[4][16 * 64];
  const int nqt = S / 64;
  const int qt = blockIdx.x % nqt, bh = blockIdx.x / nqt;
  const int b = bh >> 5, nh = bh & 31;
  const int tid = threadIdx.x, lane = tid & 63, w = tid >> 6;
  const int hi = lane >> 4, lo = lane & 15;

  // Q fragments, pre-scaled by HD^-0.5
  const u16* qg = q + ((size_t)bh * S + qt * 64 + w * 16) * HDIM;
  short8 qf[4];
#pragma unroll
  for (int ks = 0; ks < 4; ++ks) {
    short8 r = *(const short8*)(qg + (size_t)lo * HDIM + ks * 32 + hi * 8);
    union { short8 s; u16 u[8]; } t; t.s = r;
#pragma unroll
    for (int e = 0; e < 8; ++e)
      t.u[e] = f2b(b2f(t.u[e]) * 0.08838834764831845f);
    qf[ks] = t.s;
  }

  float m_i[4], l_i[4];
  f32x4 oacc[8] = {};
#pragma unroll
  for (int j = 0; j < 4; ++j) { m_i[j] = -1e30f; l_i[j] = 0.0f; }

  const u16* kg = k + (size_t)bh * S * HDIM;
  const u16* vg = qkv + (size_t)b * S * 12288 + 8192 + (size_t)nh * 128;

  // Named staging registers — never address-taken.
  uint4 k0, k1, k2, k3, v0, v1, v2, v3;
#define LOADKV(i, kr, vr, base)                                         \
  { int c = tid + (i) * 256, r = c >> 4, c8 = (c & 15) * 8;             \
    kr = *(const uint4*)(kg + (size_t)((base) + r) * HDIM + c8);        \
    vr = *(const uint4*)(vg + (size_t)((base) + r) * 12288 + c8); }
  // scatter 2 bf16 from one u32 into Vt (pure ALU extraction)
#define VSC2(u32v, d0, r)                                               \
  { int da = (d0), db = (d0) + 1;                                       \
    int ga = ((da >> 3) ^ da) & 7, gb = ((db >> 3) ^ db) & 7;           \
    Vt[da * 64 + ((((r >> 3) ^ ga) << 3) | (r & 7))] = (u16)((u32v) & 0xffff); \
    Vt[db * 64 + ((((r >> 3) ^ gb) << 3) | (r & 7))] = (u16)((u32v) >> 16); }
#define STOREKV(i, kr, vr)                                              \
  { int c = tid + (i) * 256, r = c >> 4, c8 = (c & 15) * 8;             \
    *(uint4*)&Ks[r * 128 + (c8 ^ ((r & 7) << 3))] = kr;                 \
    VSC2(vr.x, c8 + 0, r); VSC2(vr.y, c8 + 2, r);                       \
    VSC2(vr.z, c8 + 4, r); VSC2(vr.w, c8 + 6, r); }

  LOADKV(0, k0, v0, 0) LOADKV(1, k1, v1, 0)
  LOADKV(2, k2, v2, 0) LOADKV(3, k3, v3, 0)

  u16* PsW = &Ps[w][0];

  for (int kvt = 0; kvt <= qt; ++kvt) {
    __syncthreads();  // previous tile's compute fully done
    STOREKV(0, k0, v0) STOREKV(1, k1, v1)
    STOREKV(2, k2, v2) STOREKV(3, k3, v3)
    if (kvt < qt) {  // T14: issue next tile's loads; latency hides under compute
      LOADKV(0, k0, v0, (kvt + 1) * 64) LOADKV(1, k1, v1, (kvt + 1) * 64)
      LOADKV(2, k2, v2, (kvt + 1) * 64) LOADKV(3, k3, v3, (kvt + 1) * 64)
    }
    __syncthreads();

    // QK^T: sc[cb] cols = kv cb*16+lo, rows = q w*16 + hi*4 + j
    f32x4 sc[4] = {};
#pragma unroll
    for (int ks = 0; ks < 4; ++ks) {
      const int colu = ks * 32 + hi * 8;
#pragma unroll
      for (int cb = 0; cb < 4; ++cb) {
        const int row = cb * 16 + lo;
        short8 kf = *(const short8*)&Ks[row * 128 + (colu ^ ((row & 7) << 3))];
        MFMA(sc[cb], qf[ks], kf);
      }
    }

    const int qrow = qt * 64 + w * 16 + hi * 4;
    const bool diag = (kvt == qt);
#pragma unroll
    for (int cb = 0; cb < 4; ++cb) {
      const int kvc = kvt * 64 + cb * 16 + lo;
#pragma unroll
      for (int j = 0; j < 4; ++j) {
        float sv = sc[cb][j];
        if (diag && kvc > qrow + j) sv = -1e30f;
        sc[cb][j] = sv;
      }
    }
    float rmax[4], rs[4];
#pragma unroll
    for (int j = 0; j < 4; ++j) {
      rmax[j] = fmaxf(fmaxf(sc[0][j], sc[1][j]), fmaxf(sc[2][j], sc[3][j]));
      for (int d = 8; d; d >>= 1) rmax[j] = fmaxf(rmax[j], __shfl_xor(rmax[j], d));
      float mn = fmaxf(m_i[j], rmax[j]);
      float sf = __expf(m_i[j] - mn);
      m_i[j] = mn; l_i[j] *= sf;
#pragma unroll
      for (int db = 0; db < 8; ++db) oacc[db][j] *= sf;
      rs[j] = 0.0f;
    }
#pragma unroll
    for (int cb = 0; cb < 4; ++cb)
#pragma unroll
      for (int j = 0; j < 4; ++j) {
        float p = __expf(sc[cb][j] - m_i[j]);
        sc[cb][j] = p; rs[j] += p;
      }
#pragma unroll
    for (int j = 0; j < 4; ++j) {
      for (int d = 8; d; d >>= 1) rs[j] += __shfl_xor(rs[j], d);
      l_i[j] += rs[j];
    }

    // P tile (per-wave, swizzled; same-wave DS in-order => no barrier needed)
#pragma unroll
    for (int cb = 0; cb < 4; ++cb)
#pragma unroll
      for (int j = 0; j < 4; ++j) {
        const int p = hi * 4 + j;
        PsW[p * 64 + ((cb * 16 + lo) ^ ((p & 7) << 3))] = f2b(sc[cb][j]);
      }
    short8 pf0 = *(const short8*)&PsW[lo * 64 + ((hi * 8) ^ ((lo & 7) << 3))];
    short8 pf1 = *(const short8*)&PsW[lo * 64 + ((32 + hi * 8) ^ ((lo & 7) << 3))];

    // PV: B-fragments from swizzled Vt via plain b128 (conflict-free)
#pragma unroll
    for (int ks2 = 0; ks2 < 2; ++ks2) {
      const short8 pf = ks2 ? pf1 : pf0;
#pragma unroll
      for (int db = 0; db < 8; ++db) {
        const int d = db * 16 + lo;
        const int g = ((d >> 3) ^ d) & 7;
        short8 vf = *(const short8*)&Vt[d * 64 + (((ks2 * 4 + hi) ^ g) << 3)];
        MFMA(oacc[db], pf, vf);
      }
    }
  }

#pragma unroll
  for (int j = 0; j < 4; ++j) {
    float inv = 1.0f / l_i[j];
    int srow = qt * 64 + w * 16 + hi * 4 + j;
    size_t base = ((size_t)b * S + srow) * H + (size_t)nh * HDIM + lo;
#pragma unroll
    for (int db = 0; db < 8; ++db)
      o[base + db * 16] = f2b(oacc[db][j] * inv);
  }
}

extern "C" void kernel_launch(void* const* d_in, const int* in_sizes, int n_in,
                              void* d_out, int out_size, void* d_ws, size_t ws_size,
                              hipStream_t stream) {
  const int* pos = (const int*)d_in[0];
  const float* hs = (const float*)d_in[1];
  const float* wpack = (const float*)d_in[2];
  const float* wo = (const float*)d_in[3];
  float* out = (float*)d_out;
  char* ws = (char*)d_ws;
  u16* hs_b    = (u16*)(ws + 0UL);
  u16* wpack_b = (u16*)(ws + 33554432UL);
  u16* wo_b    = (u16*)(ws + 134217728UL);
  u16* qkv_b   = (u16*)(ws + 167772160UL);
  u16* q_r     = (u16*)(ws + 268435456UL);
  u16* k_r     = (u16*)(ws + 301989888UL);
  u16* attn_b  = (u16*)(ws + 335544320UL);

  cvt_bf16<<<16384, 256, 0, stream>>>(hs, hs_b);
  cvt_bf16<<<49152, 256, 0, stream>>>(wpack, wpack_b);
  cvt_bf16<<<16384, 256, 0, stream>>>(wo, wo_b);
  gemm_bt<false><<<32 * 96, 256, 0, stream>>>(hs_b, wpack_b, qkv_b, 4096, 12288, 4096);
  rope_qk<<<4096, 256, 0, stream>>>(qkv_b, pos, q_r, k_r);
  flash_fwd<<<64 * 32, 256, 0, stream>>>(q_r, k_r, qkv_b, attn_b);
  gemm_bt<true><<<32 * 32, 256, 0, stream>>>(attn_b, wo_b, out, 4096, 4096, 4096);
}

// Round 6
// 1487.803 us; speedup vs baseline: 1.4336x; 1.4336x over previous
//
#include <hip/hip_runtime.h>

typedef short short8 __attribute__((ext_vector_type(8)));
typedef float f32x4 __attribute__((ext_vector_type(4)));
typedef unsigned short u16;

static constexpr int BATCH = 2, S = 2048, H = 4096, NHEAD = 32, HDIM = 128;

__device__ __forceinline__ u16 f2b(float f) {
  union { float f; unsigned u; } v; v.f = f;
  return (u16)((v.u + 0x7fffu + ((v.u >> 16) & 1u)) >> 16);
}
__device__ __forceinline__ float b2f(u16 h) {
  union { unsigned u; float f; } v; v.u = ((unsigned)h) << 16;
  return v.f;
}

__device__ __forceinline__ void gl16(const u16* g, u16* l) {
  __builtin_amdgcn_global_load_lds((__attribute__((address_space(1))) void*)g,
                                   (__attribute__((address_space(3))) void*)l,
                                   16, 0, 0);
}

#define MFMA(acc, a, b) \
  acc = __builtin_amdgcn_mfma_f32_16x16x32_bf16(a, b, acc, 0, 0, 0)

// ---- f32 -> bf16 convert, 4 elems/thread, exact grid ----
__global__ __launch_bounds__(256) void cvt_bf16(const float* __restrict__ in,
                                                u16* __restrict__ out) {
  size_t i = ((size_t)blockIdx.x * 256 + threadIdx.x) * 4;
  float4 v = *(const float4*)(in + i);
  ushort4 o = { f2b(v.x), f2b(v.y), f2b(v.z), f2b(v.w) };
  *(ushort4*)(out + i) = o;
}

// ---- NT GEMM: C[M][N] = A[M][K] * B[N][K]^T (both K-contiguous bf16) ----
template <bool F32OUT>
__global__ __launch_bounds__(256) void gemm_bt(const u16* __restrict__ A,
                                               const u16* __restrict__ B,
                                               void* __restrict__ C,
                                               int M, int N, int K) {
  __shared__ u16 As[128 * 32];
  __shared__ u16 Bs[128 * 32];
  const int nbn = N >> 7;
  const int bm = blockIdx.x / nbn, bn = blockIdx.x % nbn;
  const int tid = threadIdx.x, lane = tid & 63;
  const int w = tid >> 6, wr = w >> 1, wc = w & 1;
  const int hi = lane >> 4, lo = lane & 15;
  f32x4 acc[4][4] = {};
  const u16* Ag = A + (size_t)bm * 128 * K;
  const u16* Bg = B + (size_t)bn * 128 * K;
  const int c0 = tid, c1 = tid + 256;
  const u16* a0 = Ag + (size_t)(c0 >> 2) * K + (c0 & 3) * 8;
  const u16* a1 = Ag + (size_t)(c1 >> 2) * K + (c1 & 3) * 8;
  const u16* b0 = Bg + (size_t)(c0 >> 2) * K + (c0 & 3) * 8;
  const u16* b1 = Bg + (size_t)(c1 >> 2) * K + (c1 & 3) * 8;
  u16* la0 = &As[c0 * 8]; u16* la1 = &As[c1 * 8];
  u16* lb0 = &Bs[c0 * 8]; u16* lb1 = &Bs[c1 * 8];
  for (int kt = 0; kt < K; kt += 32) {
    __syncthreads();
    gl16(a0 + kt, la0); gl16(a1 + kt, la1);
    gl16(b0 + kt, lb0); gl16(b1 + kt, lb1);
    __syncthreads();
    short8 af[4], bf[4];
#pragma unroll
    for (int m = 0; m < 4; ++m)
      af[m] = *(const short8*)&As[(wr * 64 + m * 16 + lo) * 32 + hi * 8];
#pragma unroll
    for (int n = 0; n < 4; ++n)
      bf[n] = *(const short8*)&Bs[(wc * 64 + n * 16 + lo) * 32 + hi * 8];
#pragma unroll
    for (int m = 0; m < 4; ++m)
#pragma unroll
      for (int n = 0; n < 4; ++n)
        acc[m][n] = __builtin_amdgcn_mfma_f32_16x16x32_bf16(af[m], bf[n],
                                                            acc[m][n], 0, 0, 0);
  }
  const int r0 = bm * 128 + wr * 64 + hi * 4;
  const int col0 = bn * 128 + wc * 64 + lo;
#pragma unroll
  for (int m = 0; m < 4; ++m)
#pragma unroll
    for (int n = 0; n < 4; ++n)
#pragma unroll
      for (int j = 0; j < 4; ++j) {
        size_t idx = (size_t)(r0 + m * 16 + j) * N + col0 + n * 16;
        if (F32OUT) ((float*)C)[idx] = acc[m][n][j];
        else        ((u16*)C)[idx]   = f2b(acc[m][n][j]);
      }
}

// ---- RoPE + scatter: qkv[b][s][12288] -> q_r,k_r [b][nh][s][hd] ----
__global__ __launch_bounds__(256) void rope_qk(const u16* __restrict__ qkv,
                                               const int* __restrict__ pos,
                                               u16* __restrict__ qr,
                                               u16* __restrict__ kr) {
  __shared__ float cs[64], sn[64];
  const int bs = blockIdx.x;
  const int b = bs >> 11, s = bs & 2047;
  const int tid = threadIdx.x;
  if (tid < 64) {
    float p = (float)pos[bs];
    float freq = __powf(10000.0f, -(float)tid * (1.0f / 64.0f));
    float a = p * freq;
    sn[tid] = sinf(a);
    cs[tid] = cosf(a);
  }
  __syncthreads();
  const u16* src = qkv + (size_t)bs * 12288;
  for (int i = tid; i < 4096; i += 256) {
    int nh = i >> 7, hd = i & 127, f = hd & 63;
    float c = cs[f], sv = sn[f];
    int oth = (hd < 64) ? i + 64 : i - 64;
    size_t dst = ((size_t)(b * NHEAD + nh) * S + s) * HDIM + hd;
    float x = b2f(src[i]), xo = b2f(src[oth]);
    qr[dst] = f2b((hd < 64) ? (x * c - xo * sv) : (x * c + xo * sv));
    float xk = b2f(src[4096 + i]), xko = b2f(src[4096 + oth]);
    kr[dst] = f2b((hd < 64) ? (xk * c - xko * sv) : (xk * c + xko * sv));
  }
}

// ---- flash attention fwd, causal. 1 block = (b, h, 64 q-rows), 4 waves x 16 rows.
// Staging: load -> consume IMMEDIATELY (r1 structure; no cross-phase registers,
// no scratch — r4/r5's T14 prefetch caused 120-550 MB spill traffic at the
// allocator's 84-VGPR budget).
// Ks: XOR-swizzled [64 kv][128 d] (granule ^ (row&7)).
// Vt: V transposed [128 d][64 kv], kv-granule swizzled by g(d)=((d>>3)^d)&7;
//     write 8x ds_write_b16 (4-way banks), read b128 conflict-free.
// Ps: per-wave XOR-swizzled [16][64] (same-wave DS in-order => no barrier).
__global__ __launch_bounds__(256, 3) void flash_fwd(const u16* __restrict__ q,
                                                    const u16* __restrict__ k,
                                                    const u16* __restrict__ qkv,
                                                    u16* __restrict__ o) {
  __shared__ u16 Ks[64 * 128];
  __shared__ u16 Vt[128 * 64];
  __shared__ u16 Ps[4][16 * 64];
  const int nqt = S / 64;
  const int qt = blockIdx.x % nqt, bh = blockIdx.x / nqt;
  const int b = bh >> 5, nh = bh & 31;
  const int tid = threadIdx.x, lane = tid & 63, w = tid >> 6;
  const int hi = lane >> 4, lo = lane & 15;

  // Q fragments, pre-scaled by HD^-0.5
  const u16* qg = q + ((size_t)bh * S + qt * 64 + w * 16) * HDIM;
  short8 qf[4];
#pragma unroll
  for (int ks = 0; ks < 4; ++ks) {
    short8 r = *(const short8*)(qg + (size_t)lo * HDIM + ks * 32 + hi * 8);
    union { short8 s; u16 u[8]; } t; t.s = r;
#pragma unroll
    for (int e = 0; e < 8; ++e)
      t.u[e] = f2b(b2f(t.u[e]) * 0.08838834764831845f);
    qf[ks] = t.s;
  }

  float m_i[4], l_i[4];
  f32x4 oacc[8] = {};
#pragma unroll
  for (int j = 0; j < 4; ++j) { m_i[j] = -1e30f; l_i[j] = 0.0f; }

  const u16* kg = k + (size_t)bh * S * HDIM;
  const u16* vg = qkv + (size_t)b * S * 12288 + 8192 + (size_t)nh * 128;

  // scatter 2 bf16 from one u32 into Vt (pure ALU extraction, no addr-taken)
#define VSC2(u32v, d0, r)                                               \
  { int da = (d0), db = (d0) + 1;                                       \
    int ga = ((da >> 3) ^ da) & 7, gb = ((db >> 3) ^ db) & 7;           \
    Vt[da * 64 + ((((r >> 3) ^ ga) << 3) | (r & 7))] = (u16)((u32v) & 0xffff); \
    Vt[db * 64 + ((((r >> 3) ^ gb) << 3) | (r & 7))] = (u16)((u32v) >> 16); }

  u16* PsW = &Ps[w][0];

  for (int kvt = 0; kvt <= qt; ++kvt) {
    __syncthreads();  // previous tile's compute fully done
#pragma unroll
    for (int i = 0; i < 4; ++i) {  // load -> LDS immediately (short live range)
      int c = tid + i * 256, r = c >> 4, c8 = (c & 15) * 8;
      uint4 kk = *(const uint4*)(kg + (size_t)(kvt * 64 + r) * HDIM + c8);
      *(uint4*)&Ks[r * 128 + (c8 ^ ((r & 7) << 3))] = kk;
      uint4 vv = *(const uint4*)(vg + (size_t)(kvt * 64 + r) * 12288 + c8);
      VSC2(vv.x, c8 + 0, r); VSC2(vv.y, c8 + 2, r);
      VSC2(vv.z, c8 + 4, r); VSC2(vv.w, c8 + 6, r);
    }
    __syncthreads();

    // QK^T: sc[cb] cols = kv cb*16+lo, rows = q w*16 + hi*4 + j
    f32x4 sc[4] = {};
#pragma unroll
    for (int ks = 0; ks < 4; ++ks) {
      const int colu = ks * 32 + hi * 8;
#pragma unroll
      for (int cb = 0; cb < 4; ++cb) {
        const int row = cb * 16 + lo;
        short8 kf = *(const short8*)&Ks[row * 128 + (colu ^ ((row & 7) << 3))];
        MFMA(sc[cb], qf[ks], kf);
      }
    }

    const int qrow = qt * 64 + w * 16 + hi * 4;
    const bool diag = (kvt == qt);
#pragma unroll
    for (int cb = 0; cb < 4; ++cb) {
      const int kvc = kvt * 64 + cb * 16 + lo;
#pragma unroll
      for (int j = 0; j < 4; ++j) {
        float sv = sc[cb][j];
        if (diag && kvc > qrow + j) sv = -1e30f;
        sc[cb][j] = sv;
      }
    }
    float rmax[4], rs[4];
#pragma unroll
    for (int j = 0; j < 4; ++j) {
      rmax[j] = fmaxf(fmaxf(sc[0][j], sc[1][j]), fmaxf(sc[2][j], sc[3][j]));
      for (int d = 8; d; d >>= 1) rmax[j] = fmaxf(rmax[j], __shfl_xor(rmax[j], d));
      float mn = fmaxf(m_i[j], rmax[j]);
      float sf = __expf(m_i[j] - mn);
      m_i[j] = mn; l_i[j] *= sf;
#pragma unroll
      for (int db = 0; db < 8; ++db) oacc[db][j] *= sf;
      rs[j] = 0.0f;
    }
#pragma unroll
    for (int cb = 0; cb < 4; ++cb)
#pragma unroll
      for (int j = 0; j < 4; ++j) {
        float p = __expf(sc[cb][j] - m_i[j]);
        sc[cb][j] = p; rs[j] += p;
      }
#pragma unroll
    for (int j = 0; j < 4; ++j) {
      for (int d = 8; d; d >>= 1) rs[j] += __shfl_xor(rs[j], d);
      l_i[j] += rs[j];
    }

    // P tile (per-wave, swizzled; same-wave DS in-order => no barrier needed)
#pragma unroll
    for (int cb = 0; cb < 4; ++cb)
#pragma unroll
      for (int j = 0; j < 4; ++j) {
        const int p = hi * 4 + j;
        PsW[p * 64 + ((cb * 16 + lo) ^ ((p & 7) << 3))] = f2b(sc[cb][j]);
      }
    short8 pf0 = *(const short8*)&PsW[lo * 64 + ((hi * 8) ^ ((lo & 7) << 3))];
    short8 pf1 = *(const short8*)&PsW[lo * 64 + ((32 + hi * 8) ^ ((lo & 7) << 3))];

    // PV: B-fragments from swizzled Vt via plain b128 (conflict-free)
#pragma unroll
    for (int ks2 = 0; ks2 < 2; ++ks2) {
      const short8 pf = ks2 ? pf1 : pf0;
#pragma unroll
      for (int db = 0; db < 8; ++db) {
        const int d = db * 16 + lo;
        const int g = ((d >> 3) ^ d) & 7;
        short8 vf = *(const short8*)&Vt[d * 64 + (((ks2 * 4 + hi) ^ g) << 3)];
        MFMA(oacc[db], pf, vf);
      }
    }
  }

#pragma unroll
  for (int j = 0; j < 4; ++j) {
    float inv = 1.0f / l_i[j];
    int srow = qt * 64 + w * 16 + hi * 4 + j;
    size_t base = ((size_t)b * S + srow) * H + (size_t)nh * HDIM + lo;
#pragma unroll
    for (int db = 0; db < 8; ++db)
      o[base + db * 16] = f2b(oacc[db][j] * inv);
  }
}

extern "C" void kernel_launch(void* const* d_in, const int* in_sizes, int n_in,
                              void* d_out, int out_size, void* d_ws, size_t ws_size,
                              hipStream_t stream) {
  const int* pos = (const int*)d_in[0];
  const float* hs = (const float*)d_in[1];
  const float* wpack = (const float*)d_in[2];
  const float* wo = (const float*)d_in[3];
  float* out = (float*)d_out;
  char* ws = (char*)d_ws;
  u16* hs_b    = (u16*)(ws + 0UL);
  u16* wpack_b = (u16*)(ws + 33554432UL);
  u16* wo_b    = (u16*)(ws + 134217728UL);
  u16* qkv_b   = (u16*)(ws + 167772160UL);
  u16* q_r     = (u16*)(ws + 268435456UL);
  u16* k_r     = (u16*)(ws + 301989888UL);
  u16* attn_b  = (u16*)(ws + 335544320UL);

  cvt_bf16<<<16384, 256, 0, stream>>>(hs, hs_b);
  cvt_bf16<<<49152, 256, 0, stream>>>(wpack, wpack_b);
  cvt_bf16<<<16384, 256, 0, stream>>>(wo, wo_b);
  gemm_bt<false><<<32 * 96, 256, 0, stream>>>(hs_b, wpack_b, qkv_b, 4096, 12288, 4096);
  rope_qk<<<4096, 256, 0, stream>>>(qkv_b, pos, q_r, k_r);
  flash_fwd<<<64 * 32, 256, 0, stream>>>(q_r, k_r, qkv_b, attn_b);
  gemm_bt<true><<<32 * 32, 256, 0, stream>>>(attn_b, wo_b, out, 4096, 4096, 4096);
}

// Round 7
// 1136.978 us; speedup vs baseline: 1.8759x; 1.3086x over previous
//
#include <hip/hip_runtime.h>

typedef short short8 __attribute__((ext_vector_type(8)));
typedef float f32x4 __attribute__((ext_vector_type(4)));
typedef unsigned short u16;

static constexpr int BATCH = 2, S = 2048, H = 4096, NHEAD = 32, HDIM = 128;

__device__ __forceinline__ u16 f2b(float f) {
  union { float f; unsigned u; } v; v.f = f;
  return (u16)((v.u + 0x7fffu + ((v.u >> 16) & 1u)) >> 16);
}
__device__ __forceinline__ float b2f(u16 h) {
  union { unsigned u; float f; } v; v.u = ((unsigned)h) << 16;
  return v.f;
}

__device__ __forceinline__ void gl16(const u16* g, u16* l) {
  __builtin_amdgcn_global_load_lds((__attribute__((address_space(1))) void*)g,
                                   (__attribute__((address_space(3))) void*)l,
                                   16, 0, 0);
}

#define MFMA(acc, a, b) \
  acc = __builtin_amdgcn_mfma_f32_16x16x32_bf16(a, b, acc, 0, 0, 0)

// ---- f32 -> bf16 convert, 4 elems/thread, exact grid ----
__global__ __launch_bounds__(256) void cvt_bf16(const float* __restrict__ in,
                                                u16* __restrict__ out) {
  size_t i = ((size_t)blockIdx.x * 256 + threadIdx.x) * 4;
  float4 v = *(const float4*)(in + i);
  ushort4 o = { f2b(v.x), f2b(v.y), f2b(v.z), f2b(v.w) };
  *(ushort4*)(out + i) = o;
}

// ---- NT GEMM: C[M][N] = A[M][K] * B[N][K]^T (both K-contiguous bf16) ----
template <bool F32OUT>
__global__ __launch_bounds__(256) void gemm_bt(const u16* __restrict__ A,
                                               const u16* __restrict__ B,
                                               void* __restrict__ C,
                                               int M, int N, int K) {
  __shared__ u16 As[128 * 32];
  __shared__ u16 Bs[128 * 32];
  const int nbn = N >> 7;
  const int bm = blockIdx.x / nbn, bn = blockIdx.x % nbn;
  const int tid = threadIdx.x, lane = tid & 63;
  const int w = tid >> 6, wr = w >> 1, wc = w & 1;
  const int hi = lane >> 4, lo = lane & 15;
  f32x4 acc[4][4] = {};
  const u16* Ag = A + (size_t)bm * 128 * K;
  const u16* Bg = B + (size_t)bn * 128 * K;
  const int c0 = tid, c1 = tid + 256;
  const u16* a0 = Ag + (size_t)(c0 >> 2) * K + (c0 & 3) * 8;
  const u16* a1 = Ag + (size_t)(c1 >> 2) * K + (c1 & 3) * 8;
  const u16* b0 = Bg + (size_t)(c0 >> 2) * K + (c0 & 3) * 8;
  const u16* b1 = Bg + (size_t)(c1 >> 2) * K + (c1 & 3) * 8;
  u16* la0 = &As[c0 * 8]; u16* la1 = &As[c1 * 8];
  u16* lb0 = &Bs[c0 * 8]; u16* lb1 = &Bs[c1 * 8];
  for (int kt = 0; kt < K; kt += 32) {
    __syncthreads();
    gl16(a0 + kt, la0); gl16(a1 + kt, la1);
    gl16(b0 + kt, lb0); gl16(b1 + kt, lb1);
    __syncthreads();
    short8 af[4], bf[4];
#pragma unroll
    for (int m = 0; m < 4; ++m)
      af[m] = *(const short8*)&As[(wr * 64 + m * 16 + lo) * 32 + hi * 8];
#pragma unroll
    for (int n = 0; n < 4; ++n)
      bf[n] = *(const short8*)&Bs[(wc * 64 + n * 16 + lo) * 32 + hi * 8];
#pragma unroll
    for (int m = 0; m < 4; ++m)
#pragma unroll
      for (int n = 0; n < 4; ++n)
        acc[m][n] = __builtin_amdgcn_mfma_f32_16x16x32_bf16(af[m], bf[n],
                                                            acc[m][n], 0, 0, 0);
  }
  const int r0 = bm * 128 + wr * 64 + hi * 4;
  const int col0 = bn * 128 + wc * 64 + lo;
#pragma unroll
  for (int m = 0; m < 4; ++m)
#pragma unroll
    for (int n = 0; n < 4; ++n)
#pragma unroll
      for (int j = 0; j < 4; ++j) {
        size_t idx = (size_t)(r0 + m * 16 + j) * N + col0 + n * 16;
        if (F32OUT) ((float*)C)[idx] = acc[m][n][j];
        else        ((u16*)C)[idx]   = f2b(acc[m][n][j]);
      }
}

// ---- RoPE + scatter: qkv[b][s][12288] -> q_r,k_r [b][nh][s][hd] ----
__global__ __launch_bounds__(256) void rope_qk(const u16* __restrict__ qkv,
                                               const int* __restrict__ pos,
                                               u16* __restrict__ qr,
                                               u16* __restrict__ kr) {
  __shared__ float cs[64], sn[64];
  const int bs = blockIdx.x;
  const int b = bs >> 11, s = bs & 2047;
  const int tid = threadIdx.x;
  if (tid < 64) {
    float p = (float)pos[bs];
    float freq = __powf(10000.0f, -(float)tid * (1.0f / 64.0f));
    float a = p * freq;
    sn[tid] = sinf(a);
    cs[tid] = cosf(a);
  }
  __syncthreads();
  const u16* src = qkv + (size_t)bs * 12288;
  for (int i = tid; i < 4096; i += 256) {
    int nh = i >> 7, hd = i & 127, f = hd & 63;
    float c = cs[f], sv = sn[f];
    int oth = (hd < 64) ? i + 64 : i - 64;
    size_t dst = ((size_t)(b * NHEAD + nh) * S + s) * HDIM + hd;
    float x = b2f(src[i]), xo = b2f(src[oth]);
    qr[dst] = f2b((hd < 64) ? (x * c - xo * sv) : (x * c + xo * sv));
    float xk = b2f(src[4096 + i]), xko = b2f(src[4096 + oth]);
    kr[dst] = f2b((hd < 64) ? (xk * c - xko * sv) : (xk * c + xko * sv));
  }
}

// ---- V -> MFMA-B-fragment order, per (bh, 64-kv block):
// chunk idx in [0,1024): f=idx>>6 (ks2=f>>3, db=f&7), l=idx&63 (hi=l>>4, lo=l&15)
// chunk holds V[kv0+ks2*32+hi*8+j][db*16+lo], j=0..7 (16B contiguous).
__global__ __launch_bounds__(256) void transpose_v(const u16* __restrict__ qkv,
                                                   u16* __restrict__ vt) {
  __shared__ u16 L[64 * 136];
  const int kb = blockIdx.x & 31, bh = blockIdx.x >> 5;
  const int b = bh >> 5, nh = bh & 31;
  const int tid = threadIdx.x;
  const u16* src = qkv + ((size_t)(b * S + kb * 64)) * 12288 + 8192 + nh * 128;
#pragma unroll
  for (int i = 0; i < 4; ++i) {
    int idx = i * 256 + tid, r = idx >> 4, gd = idx & 15;
    *(uint4*)&L[r * 136 + gd * 8] = *(const uint4*)(src + (size_t)r * 12288 + gd * 8);
  }
  __syncthreads();
  u16* dst = vt + ((size_t)bh * S + kb * 64) * 128;
#pragma unroll
  for (int i = 0; i < 4; ++i) {
    int idx = i * 256 + tid;
    int f = idx >> 6, l = idx & 63;
    int ks2 = f >> 3, db = f & 7, hi = l >> 4, lo = l & 15;
    int d = db * 16 + lo;
    int rb = (ks2 * 32 + hi * 8) * 136 + d;
    unsigned e0 = L[rb], e1 = L[rb + 136], e2 = L[rb + 272], e3 = L[rb + 408];
    unsigned e4 = L[rb + 544], e5 = L[rb + 680], e6 = L[rb + 816], e7 = L[rb + 952];
    uint4 o; o.x = e0 | (e1 << 16); o.y = e2 | (e3 << 16);
    o.z = e4 | (e5 << 16); o.w = e6 | (e7 << 16);
    *(uint4*)(dst + (size_t)idx * 8) = o;
  }
}

// ---- flash attention fwd, causal. 1 block = (b, h, 64 q-rows), 4 waves x 16 rows.
// Double-buffered DMA staging (global_load_lds), counted vmcnt(8), raw barriers:
//   KB: [64 kv][128 d], granule-swizzled via PRE-SWIZZLED GLOBAL SOURCE
//       (LDS[r][g] = K[r][g^(r&7)]); read expression same as r6.
//   VB: B-fragment order (from transpose_v); PV reads = b128 @ base+lane*16,
//       conflict-free, no in-kernel transpose.
// Ps: per-wave XOR-swizzled [16][64] (same-wave DS in-order).
__global__ __launch_bounds__(256, 2) void flash_fwd(const u16* __restrict__ q,
                                                    const u16* __restrict__ k,
                                                    const u16* __restrict__ vt,
                                                    u16* __restrict__ o) {
  __shared__ u16 KB[2][64 * 128];
  __shared__ u16 VB[2][64 * 128];
  __shared__ u16 Ps[4][16 * 64];
  const int nqt = S / 64;
  const int qt = (nqt - 1) - ((int)blockIdx.x % nqt);  // heavy blocks first
  const int bh = blockIdx.x / nqt;
  const int tid = threadIdx.x, lane = tid & 63, w = tid >> 6;
  const int hi = lane >> 4, lo = lane & 15;

  // Q fragments, pre-scaled by HD^-0.5
  const u16* qg = q + ((size_t)bh * S + qt * 64 + w * 16) * HDIM;
  short8 qf[4];
#pragma unroll
  for (int ks = 0; ks < 4; ++ks) {
    short8 r = *(const short8*)(qg + (size_t)lo * HDIM + ks * 32 + hi * 8);
    union { short8 s; u16 u[8]; } t; t.s = r;
#pragma unroll
    for (int e = 0; e < 8; ++e)
      t.u[e] = f2b(b2f(t.u[e]) * 0.08838834764831845f);
    qf[ks] = t.s;
  }

  float m_i[4], l_i[4];
  f32x4 oacc[8] = {};
#pragma unroll
  for (int j = 0; j < 4; ++j) { m_i[j] = -1e30f; l_i[j] = 0.0f; }

  const u16* kg = k + (size_t)bh * S * HDIM;
  const u16* vg = vt + (size_t)bh * S * HDIM;

  // 8 gl16/thread per tile; K source pre-swizzled, V linear fragment-order.
#define STAGE(buf, kvbase)                                                  \
  {                                                                         \
    _Pragma("unroll") for (int i = 0; i < 4; ++i) {                         \
      int idx = i * 256 + tid, r = idx >> 4, gd = idx & 15;                 \
      gl16(kg + (size_t)((kvbase) + r) * HDIM + ((gd ^ (r & 7)) * 8),       \
           &KB[buf][idx * 8]);                                              \
    }                                                                       \
    _Pragma("unroll") for (int i = 0; i < 4; ++i) {                         \
      int idx = i * 256 + tid;                                              \
      gl16(vg + (size_t)(kvbase) * HDIM + idx * 8, &VB[buf][idx * 8]);      \
    }                                                                       \
  }

  STAGE(0, 0)
  int cur = 0;
  u16* PsW = &Ps[w][0];

  for (int kvt = 0; kvt <= qt; ++kvt) {
    if (kvt < qt) {
      STAGE(cur ^ 1, (kvt + 1) * 64)
      asm volatile("s_waitcnt vmcnt(8)" ::: "memory");  // cur's DMA landed
    } else {
      asm volatile("s_waitcnt vmcnt(0)" ::: "memory");
    }
    __builtin_amdgcn_s_barrier();
    __builtin_amdgcn_sched_barrier(0);
    const u16* Kc = &KB[cur][0];
    const u16* Vc = &VB[cur][0];

    // QK^T: sc[cb] cols = kv cb*16+lo, rows = q w*16 + hi*4 + j
    f32x4 sc[4] = {};
#pragma unroll
    for (int ks = 0; ks < 4; ++ks) {
      const int colu = ks * 32 + hi * 8;
#pragma unroll
      for (int cb = 0; cb < 4; ++cb) {
        const int row = cb * 16 + lo;
        short8 kf = *(const short8*)&Kc[row * 128 + (colu ^ ((row & 7) << 3))];
        MFMA(sc[cb], qf[ks], kf);
      }
    }

    const int qrow = qt * 64 + w * 16 + hi * 4;
    const bool diag = (kvt == qt);
#pragma unroll
    for (int cb = 0; cb < 4; ++cb) {
      const int kvc = kvt * 64 + cb * 16 + lo;
#pragma unroll
      for (int j = 0; j < 4; ++j) {
        float sv = sc[cb][j];
        if (diag && kvc > qrow + j) sv = -1e30f;
        sc[cb][j] = sv;
      }
    }
    float rmax[4], rs[4];
#pragma unroll
    for (int j = 0; j < 4; ++j) {
      rmax[j] = fmaxf(fmaxf(sc[0][j], sc[1][j]), fmaxf(sc[2][j], sc[3][j]));
      for (int d = 8; d; d >>= 1) rmax[j] = fmaxf(rmax[j], __shfl_xor(rmax[j], d));
      float mn = fmaxf(m_i[j], rmax[j]);
      float sf = __expf(m_i[j] - mn);
      m_i[j] = mn; l_i[j] *= sf;
#pragma unroll
      for (int db = 0; db < 8; ++db) oacc[db][j] *= sf;
      rs[j] = 0.0f;
    }
#pragma unroll
    for (int cb = 0; cb < 4; ++cb)
#pragma unroll
      for (int j = 0; j < 4; ++j) {
        float p = __expf(sc[cb][j] - m_i[j]);
        sc[cb][j] = p; rs[j] += p;
      }
#pragma unroll
    for (int j = 0; j < 4; ++j) {
      for (int d = 8; d; d >>= 1) rs[j] += __shfl_xor(rs[j], d);
      l_i[j] += rs[j];
    }

    // P tile (per-wave, swizzled; same-wave DS in-order => no barrier needed)
#pragma unroll
    for (int cb = 0; cb < 4; ++cb)
#pragma unroll
      for (int j = 0; j < 4; ++j) {
        const int p = hi * 4 + j;
        PsW[p * 64 + ((cb * 16 + lo) ^ ((p & 7) << 3))] = f2b(sc[cb][j]);
      }
    short8 pf0 = *(const short8*)&PsW[lo * 64 + ((hi * 8) ^ ((lo & 7) << 3))];
    short8 pf1 = *(const short8*)&PsW[lo * 64 + ((32 + hi * 8) ^ ((lo & 7) << 3))];

    // PV: fragment-order VB, b128 @ base+lane*16, conflict-free
#pragma unroll
    for (int ks2 = 0; ks2 < 2; ++ks2) {
      const short8 pf = ks2 ? pf1 : pf0;
#pragma unroll
      for (int db = 0; db < 8; ++db) {
        short8 vf = *(const short8*)&Vc[((ks2 * 8 + db) * 64 + lane) * 8];
        MFMA(oacc[db], pf, vf);
      }
    }
    __builtin_amdgcn_s_barrier();  // all waves done with cur before overwrite
    cur ^= 1;
  }

#pragma unroll
  for (int j = 0; j < 4; ++j) {
    float inv = 1.0f / l_i[j];
    int srow = qt * 64 + w * 16 + hi * 4 + j;
    const int b = bh >> 5, nh = bh & 31;
    size_t base = ((size_t)b * S + srow) * H + (size_t)nh * HDIM + lo;
#pragma unroll
    for (int db = 0; db < 8; ++db)
      o[base + db * 16] = f2b(oacc[db][j] * inv);
  }
}

extern "C" void kernel_launch(void* const* d_in, const int* in_sizes, int n_in,
                              void* d_out, int out_size, void* d_ws, size_t ws_size,
                              hipStream_t stream) {
  const int* pos = (const int*)d_in[0];
  const float* hs = (const float*)d_in[1];
  const float* wpack = (const float*)d_in[2];
  const float* wo = (const float*)d_in[3];
  float* out = (float*)d_out;
  char* ws = (char*)d_ws;
  u16* hs_b    = (u16*)(ws + 0UL);          // dead after gemm1 -> reused as v_t
  u16* wpack_b = (u16*)(ws + 33554432UL);
  u16* wo_b    = (u16*)(ws + 134217728UL);
  u16* qkv_b   = (u16*)(ws + 167772160UL);
  u16* q_r     = (u16*)(ws + 268435456UL);
  u16* k_r     = (u16*)(ws + 301989888UL);
  u16* attn_b  = (u16*)(ws + 335544320UL);
  u16* v_t     = hs_b;

  cvt_bf16<<<16384, 256, 0, stream>>>(hs, hs_b);
  cvt_bf16<<<49152, 256, 0, stream>>>(wpack, wpack_b);
  cvt_bf16<<<16384, 256, 0, stream>>>(wo, wo_b);
  gemm_bt<false><<<32 * 96, 256, 0, stream>>>(hs_b, wpack_b, qkv_b, 4096, 12288, 4096);
  rope_qk<<<4096, 256, 0, stream>>>(qkv_b, pos, q_r, k_r);
  transpose_v<<<2048, 256, 0, stream>>>(qkv_b, v_t);
  flash_fwd<<<64 * 32, 256, 0, stream>>>(q_r, k_r, v_t, attn_b);
  gemm_bt<true><<<32 * 32, 256, 0, stream>>>(attn_b, wo_b, out, 4096, 4096, 4096);
}

// Round 8
// 974.647 us; speedup vs baseline: 2.1883x; 1.1666x over previous
//
#include <hip/hip_runtime.h>

typedef short short8 __attribute__((ext_vector_type(8)));
typedef float f32x4 __attribute__((ext_vector_type(4)));
typedef unsigned short u16;

static constexpr int BATCH = 2, S = 2048, H = 4096, NHEAD = 32, HDIM = 128;

__device__ __forceinline__ u16 f2b(float f) {
  union { float f; unsigned u; } v; v.f = f;
  return (u16)((v.u + 0x7fffu + ((v.u >> 16) & 1u)) >> 16);
}
__device__ __forceinline__ float b2f(u16 h) {
  union { unsigned u; float f; } v; v.u = ((unsigned)h) << 16;
  return v.f;
}

__device__ __forceinline__ void gl16(const u16* g, u16* l) {
  __builtin_amdgcn_global_load_lds((__attribute__((address_space(1))) void*)g,
                                   (__attribute__((address_space(3))) void*)l,
                                   16, 0, 0);
}

#define MFMA(acc, a, b) \
  acc = __builtin_amdgcn_mfma_f32_16x16x32_bf16(a, b, acc, 0, 0, 0)

// ---- f32 -> bf16 convert, 4 elems/thread, exact grid ----
__global__ __launch_bounds__(256) void cvt_bf16(const float* __restrict__ in,
                                                u16* __restrict__ out) {
  size_t i = ((size_t)blockIdx.x * 256 + threadIdx.x) * 4;
  float4 v = *(const float4*)(in + i);
  ushort4 o = { f2b(v.x), f2b(v.y), f2b(v.z), f2b(v.w) };
  *(ushort4*)(out + i) = o;
}

// ---- 256x256 8-phase NT GEMM: C[M][N] = A[M][K]*B[N][K]^T, bf16 in.
// 512 thr = 8 waves (2 wm x 4 wn); per-wave C = 128x64 (acc[8][4]).
// BK=64; K-tile t: 4 phases, each {ds_read frags | stage 1 half-tile |
// lgkmcnt(0); barrier; setprio; 16 MFMA; setprio; barrier}.
// Stage stream: A1(t+1)@f1, B0(t+1)@f2, B1(t+1)@f3, A0(t+2)@f4; vmcnt(2)@f4.
// LDS 128 KiB: A,B each [2 buf][2 half][128x64], granule^(row&7) swizzle via
// pre-swizzled global source (DMA dest linear).
template <bool F32OUT>
__global__ __launch_bounds__(512, 2) void gemm256(const u16* __restrict__ A,
                                                  const u16* __restrict__ B,
                                                  void* __restrict__ C,
                                                  int M, int N, int K) {
  __shared__ u16 AL[2][2][128 * 64];
  __shared__ u16 BL[2][2][128 * 64];
  const int nbn = N >> 8;
  const int nwg = (M >> 8) * nbn;
  const int bid = blockIdx.x;
  const int wg = (bid & 7) * (nwg >> 3) + (bid >> 3);  // XCD swizzle (nwg%8==0)
  const int bm = wg / nbn, bn = wg % nbn;
  const int tid = threadIdx.x, lane = tid & 63;
  const int w = tid >> 6, wm = w >> 2, wn = w & 3;
  const int hi = lane >> 4, lo = lane & 15;
  const int nk = K >> 6;

  const u16* Abase = A + (size_t)(bm * 256) * K;
  const u16* Bbase = B + (size_t)(bn * 256) * K;

  // half-tile = 128 rows x 64 cols; chunk c in [0,1024): row=c>>3, slot=c&7;
  // global col granule = slot ^ (row&7); LDS dest linear.
#define STG_A(buf, half, kt)                                                   \
  { _Pragma("unroll") for (int i = 0; i < 2; ++i) {                            \
      int c = tid + i * 512, r = c >> 3, s = c & 7;                            \
      gl16(Abase + (size_t)((half) * 128 + r) * K + (kt) * 64 +                \
               ((s ^ (r & 7)) * 8),                                            \
           &AL[buf][half][c * 8]);                                             \
    } }
#define STG_B(buf, half, kt)                                                   \
  { _Pragma("unroll") for (int i = 0; i < 2; ++i) {                            \
      int c = tid + i * 512, r = c >> 3, s = c & 7;                            \
      gl16(Bbase + (size_t)((half) * 128 + r) * K + (kt) * 64 +                \
               ((s ^ (r & 7)) * 8),                                            \
           &BL[buf][half][c * 8]);                                             \
    } }
#define LGKM0()                                                                \
  do { asm volatile("s_waitcnt lgkmcnt(0)" ::: "memory");                      \
       __builtin_amdgcn_sched_barrier(0); } while (0)

  f32x4 acc[8][4] = {};

  // prologue: all of K-tile 0 + A0(1); wait all but newest pair
  STG_A(0, 0, 0) STG_A(0, 1, 0) STG_B(0, 0, 0) STG_B(0, 1, 0)
  if (nk > 1) STG_A(1, 0, 1)
  asm volatile("s_waitcnt vmcnt(2)" ::: "memory");
  __builtin_amdgcn_sched_barrier(0);
  __builtin_amdgcn_s_barrier();

  short8 af[4][2], bf[2][2][2];  // af[mi][ks]; bf[nh][ni][ks]

  for (int t = 0; t < nk; ++t) {
    const int cur = t & 1;
    const u16* Awave = &AL[cur][wm][0];
    const u16* Bwave = &BL[cur][wn >> 1][0];
    const int lrB = (wn & 1) * 64;

    // ---- f1: read A mh0 (8 b128) + B nh0 (4 b128); stage A1(t+1)
#pragma unroll
    for (int mi = 0; mi < 4; ++mi)
#pragma unroll
      for (int ks = 0; ks < 2; ++ks)
        af[mi][ks] = *(const short8*)&Awave[(mi * 16 + lo) * 64 +
                                            (((ks * 4 + hi) ^ (lo & 7)) * 8)];
#pragma unroll
    for (int ni = 0; ni < 2; ++ni)
#pragma unroll
      for (int ks = 0; ks < 2; ++ks)
        bf[0][ni][ks] = *(const short8*)&Bwave[(lrB + ni * 16 + lo) * 64 +
                                               (((ks * 4 + hi) ^ (lo & 7)) * 8)];
    if (t + 1 < nk) STG_A(cur ^ 1, 1, t + 1)
    LGKM0();
    __builtin_amdgcn_s_barrier();
    __builtin_amdgcn_s_setprio(1);
#pragma unroll
    for (int mi = 0; mi < 4; ++mi)
#pragma unroll
      for (int ni = 0; ni < 2; ++ni)
#pragma unroll
        for (int ks = 0; ks < 2; ++ks)
          MFMA(acc[mi][ni], af[mi][ks], bf[0][ni][ks]);
    __builtin_amdgcn_s_setprio(0);
    __builtin_amdgcn_s_barrier();

    // ---- f2: read B nh1 (4 b128); stage B0(t+1)
#pragma unroll
    for (int ni = 0; ni < 2; ++ni)
#pragma unroll
      for (int ks = 0; ks < 2; ++ks)
        bf[1][ni][ks] = *(const short8*)&Bwave[(lrB + 32 + ni * 16 + lo) * 64 +
                                               (((ks * 4 + hi) ^ (lo & 7)) * 8)];
    if (t + 1 < nk) STG_B(cur ^ 1, 0, t + 1)
    LGKM0();
    __builtin_amdgcn_s_barrier();
    __builtin_amdgcn_s_setprio(1);
#pragma unroll
    for (int mi = 0; mi < 4; ++mi)
#pragma unroll
      for (int ni = 0; ni < 2; ++ni)
#pragma unroll
        for (int ks = 0; ks < 2; ++ks)
          MFMA(acc[mi][2 + ni], af[mi][ks], bf[1][ni][ks]);
    __builtin_amdgcn_s_setprio(0);
    __builtin_amdgcn_s_barrier();

    // ---- f3: read A mh1 (8 b128); stage B1(t+1)
#pragma unroll
    for (int mi = 0; mi < 4; ++mi)
#pragma unroll
      for (int ks = 0; ks < 2; ++ks)
        af[mi][ks] = *(const short8*)&Awave[((64 + mi * 16 + lo)) * 64 +
                                            (((ks * 4 + hi) ^ (lo & 7)) * 8)];
    if (t + 1 < nk) STG_B(cur ^ 1, 1, t + 1)
    LGKM0();
    __builtin_amdgcn_s_barrier();
    __builtin_amdgcn_s_setprio(1);
#pragma unroll
    for (int mi = 0; mi < 4; ++mi)
#pragma unroll
      for (int ni = 0; ni < 2; ++ni)
#pragma unroll
        for (int ks = 0; ks < 2; ++ks)
          MFMA(acc[4 + mi][2 + ni], af[mi][ks], bf[1][ni][ks]);
    __builtin_amdgcn_s_setprio(0);
    __builtin_amdgcn_s_barrier();

    // ---- f4: no ds_read (reuse bf[0]); stage A0(t+2); counted vmcnt
    if (t + 2 < nk) {
      STG_A(cur, 0, t + 2)
      asm volatile("s_waitcnt vmcnt(2)" ::: "memory");
    } else {
      asm volatile("s_waitcnt vmcnt(0)" ::: "memory");
    }
    __builtin_amdgcn_sched_barrier(0);
    __builtin_amdgcn_s_barrier();
    __builtin_amdgcn_s_setprio(1);
#pragma unroll
    for (int mi = 0; mi < 4; ++mi)
#pragma unroll
      for (int ni = 0; ni < 2; ++ni)
#pragma unroll
        for (int ks = 0; ks < 2; ++ks)
          MFMA(acc[4 + mi][ni], af[mi][ks], bf[0][ni][ks]);
    __builtin_amdgcn_s_setprio(0);
    __builtin_amdgcn_s_barrier();
  }

  // epilogue: C[row][col], row = bm*256+wm*128+mf*16+hi*4+j, col = bn*256+wn*64+nf*16+lo
#pragma unroll
  for (int mf = 0; mf < 8; ++mf)
#pragma unroll
    for (int nf = 0; nf < 4; ++nf)
#pragma unroll
      for (int j = 0; j < 4; ++j) {
        size_t idx = (size_t)(bm * 256 + wm * 128 + mf * 16 + hi * 4 + j) * N +
                     bn * 256 + wn * 64 + nf * 16 + lo;
        if (F32OUT) ((float*)C)[idx] = acc[mf][nf][j];
        else        ((u16*)C)[idx]   = f2b(acc[mf][nf][j]);
      }
}

// ---- RoPE + scatter: qkv[b][s][12288] -> q_r,k_r [b][nh][s][hd] ----
__global__ __launch_bounds__(256) void rope_qk(const u16* __restrict__ qkv,
                                               const int* __restrict__ pos,
                                               u16* __restrict__ qr,
                                               u16* __restrict__ kr) {
  __shared__ float cs[64], sn[64];
  const int bs = blockIdx.x;
  const int b = bs >> 11, s = bs & 2047;
  const int tid = threadIdx.x;
  if (tid < 64) {
    float p = (float)pos[bs];
    float freq = __powf(10000.0f, -(float)tid * (1.0f / 64.0f));
    float a = p * freq;
    sn[tid] = sinf(a);
    cs[tid] = cosf(a);
  }
  __syncthreads();
  const u16* src = qkv + (size_t)bs * 12288;
  for (int i = tid; i < 4096; i += 256) {
    int nh = i >> 7, hd = i & 127, f = hd & 63;
    float c = cs[f], sv = sn[f];
    int oth = (hd < 64) ? i + 64 : i - 64;
    size_t dst = ((size_t)(b * NHEAD + nh) * S + s) * HDIM + hd;
    float x = b2f(src[i]), xo = b2f(src[oth]);
    qr[dst] = f2b((hd < 64) ? (x * c - xo * sv) : (x * c + xo * sv));
    float xk = b2f(src[4096 + i]), xko = b2f(src[4096 + oth]);
    kr[dst] = f2b((hd < 64) ? (xk * c - xko * sv) : (xk * c + xko * sv));
  }
}

// ---- V -> MFMA-B-fragment order, per (bh, 64-kv block) ----
__global__ __launch_bounds__(256) void transpose_v(const u16* __restrict__ qkv,
                                                   u16* __restrict__ vt) {
  __shared__ u16 L[64 * 136];
  const int kb = blockIdx.x & 31, bh = blockIdx.x >> 5;
  const int b = bh >> 5, nh = bh & 31;
  const int tid = threadIdx.x;
  const u16* src = qkv + ((size_t)(b * S + kb * 64)) * 12288 + 8192 + nh * 128;
#pragma unroll
  for (int i = 0; i < 4; ++i) {
    int idx = i * 256 + tid, r = idx >> 4, gd = idx & 15;
    *(uint4*)&L[r * 136 + gd * 8] = *(const uint4*)(src + (size_t)r * 12288 + gd * 8);
  }
  __syncthreads();
  u16* dst = vt + ((size_t)bh * S + kb * 64) * 128;
#pragma unroll
  for (int i = 0; i < 4; ++i) {
    int idx = i * 256 + tid;
    int f = idx >> 6, l = idx & 63;
    int ks2 = f >> 3, db = f & 7, hi = l >> 4, lo = l & 15;
    int d = db * 16 + lo;
    int rb = (ks2 * 32 + hi * 8) * 136 + d;
    unsigned e0 = L[rb], e1 = L[rb + 136], e2 = L[rb + 272], e3 = L[rb + 408];
    unsigned e4 = L[rb + 544], e5 = L[rb + 680], e6 = L[rb + 816], e7 = L[rb + 952];
    uint4 o; o.x = e0 | (e1 << 16); o.y = e2 | (e3 << 16);
    o.z = e4 | (e5 << 16); o.w = e6 | (e7 << 16);
    *(uint4*)(dst + (size_t)idx * 8) = o;
  }
}

// ---- flash attention fwd, causal (r7 structure, unchanged) ----
__global__ __launch_bounds__(256, 2) void flash_fwd(const u16* __restrict__ q,
                                                    const u16* __restrict__ k,
                                                    const u16* __restrict__ vt,
                                                    u16* __restrict__ o) {
  __shared__ u16 KB[2][64 * 128];
  __shared__ u16 VB[2][64 * 128];
  __shared__ u16 Ps[4][16 * 64];
  const int nqt = S / 64;
  const int qt = (nqt - 1) - ((int)blockIdx.x % nqt);
  const int bh = blockIdx.x / nqt;
  const int tid = threadIdx.x, lane = tid & 63, w = tid >> 6;
  const int hi = lane >> 4, lo = lane & 15;

  const u16* qg = q + ((size_t)bh * S + qt * 64 + w * 16) * HDIM;
  short8 qf[4];
#pragma unroll
  for (int ks = 0; ks < 4; ++ks) {
    short8 r = *(const short8*)(qg + (size_t)lo * HDIM + ks * 32 + hi * 8);
    union { short8 s; u16 u[8]; } t; t.s = r;
#pragma unroll
    for (int e = 0; e < 8; ++e)
      t.u[e] = f2b(b2f(t.u[e]) * 0.08838834764831845f);
    qf[ks] = t.s;
  }

  float m_i[4], l_i[4];
  f32x4 oacc[8] = {};
#pragma unroll
  for (int j = 0; j < 4; ++j) { m_i[j] = -1e30f; l_i[j] = 0.0f; }

  const u16* kg = k + (size_t)bh * S * HDIM;
  const u16* vg = vt + (size_t)bh * S * HDIM;

#define STAGE(buf, kvbase)                                                  \
  {                                                                         \
    _Pragma("unroll") for (int i = 0; i < 4; ++i) {                         \
      int idx = i * 256 + tid, r = idx >> 4, gd = idx & 15;                 \
      gl16(kg + (size_t)((kvbase) + r) * HDIM + ((gd ^ (r & 7)) * 8),       \
           &KB[buf][idx * 8]);                                              \
    }                                                                       \
    _Pragma("unroll") for (int i = 0; i < 4; ++i) {                         \
      int idx = i * 256 + tid;                                              \
      gl16(vg + (size_t)(kvbase) * HDIM + idx * 8, &VB[buf][idx * 8]);      \
    }                                                                       \
  }

  STAGE(0, 0)
  int cur = 0;
  u16* PsW = &Ps[w][0];

  for (int kvt = 0; kvt <= qt; ++kvt) {
    if (kvt < qt) {
      STAGE(cur ^ 1, (kvt + 1) * 64)
      asm volatile("s_waitcnt vmcnt(8)" ::: "memory");
    } else {
      asm volatile("s_waitcnt vmcnt(0)" ::: "memory");
    }
    __builtin_amdgcn_s_barrier();
    __builtin_amdgcn_sched_barrier(0);
    const u16* Kc = &KB[cur][0];
    const u16* Vc = &VB[cur][0];

    f32x4 sc[4] = {};
#pragma unroll
    for (int ks = 0; ks < 4; ++ks) {
      const int colu = ks * 32 + hi * 8;
#pragma unroll
      for (int cb = 0; cb < 4; ++cb) {
        const int row = cb * 16 + lo;
        short8 kf = *(const short8*)&Kc[row * 128 + (colu ^ ((row & 7) << 3))];
        MFMA(sc[cb], qf[ks], kf);
      }
    }

    const int qrow = qt * 64 + w * 16 + hi * 4;
    const bool diag = (kvt == qt);
#pragma unroll
    for (int cb = 0; cb < 4; ++cb) {
      const int kvc = kvt * 64 + cb * 16 + lo;
#pragma unroll
      for (int j = 0; j < 4; ++j) {
        float sv = sc[cb][j];
        if (diag && kvc > qrow + j) sv = -1e30f;
        sc[cb][j] = sv;
      }
    }
    float rmax[4], rs[4];
#pragma unroll
    for (int j = 0; j < 4; ++j) {
      rmax[j] = fmaxf(fmaxf(sc[0][j], sc[1][j]), fmaxf(sc[2][j], sc[3][j]));
      for (int d = 8; d; d >>= 1) rmax[j] = fmaxf(rmax[j], __shfl_xor(rmax[j], d));
      float mn = fmaxf(m_i[j], rmax[j]);
      float sf = __expf(m_i[j] - mn);
      m_i[j] = mn; l_i[j] *= sf;
#pragma unroll
      for (int db = 0; db < 8; ++db) oacc[db][j] *= sf;
      rs[j] = 0.0f;
    }
#pragma unroll
    for (int cb = 0; cb < 4; ++cb)
#pragma unroll
      for (int j = 0; j < 4; ++j) {
        float p = __expf(sc[cb][j] - m_i[j]);
        sc[cb][j] = p; rs[j] += p;
      }
#pragma unroll
    for (int j = 0; j < 4; ++j) {
      for (int d = 8; d; d >>= 1) rs[j] += __shfl_xor(rs[j], d);
      l_i[j] += rs[j];
    }

#pragma unroll
    for (int cb = 0; cb < 4; ++cb)
#pragma unroll
      for (int j = 0; j < 4; ++j) {
        const int p = hi * 4 + j;
        PsW[p * 64 + ((cb * 16 + lo) ^ ((p & 7) << 3))] = f2b(sc[cb][j]);
      }
    short8 pf0 = *(const short8*)&PsW[lo * 64 + ((hi * 8) ^ ((lo & 7) << 3))];
    short8 pf1 = *(const short8*)&PsW[lo * 64 + ((32 + hi * 8) ^ ((lo & 7) << 3))];

#pragma unroll
    for (int ks2 = 0; ks2 < 2; ++ks2) {
      const short8 pf = ks2 ? pf1 : pf0;
#pragma unroll
      for (int db = 0; db < 8; ++db) {
        short8 vf = *(const short8*)&Vc[((ks2 * 8 + db) * 64 + lane) * 8];
        MFMA(oacc[db], pf, vf);
      }
    }
    __builtin_amdgcn_s_barrier();
    cur ^= 1;
  }

#pragma unroll
  for (int j = 0; j < 4; ++j) {
    float inv = 1.0f / l_i[j];
    int srow = qt * 64 + w * 16 + hi * 4 + j;
    const int b = bh >> 5, nh = bh & 31;
    size_t base = ((size_t)b * S + srow) * H + (size_t)nh * HDIM + lo;
#pragma unroll
    for (int db = 0; db < 8; ++db)
      o[base + db * 16] = f2b(oacc[db][j] * inv);
  }
}

extern "C" void kernel_launch(void* const* d_in, const int* in_sizes, int n_in,
                              void* d_out, int out_size, void* d_ws, size_t ws_size,
                              hipStream_t stream) {
  const int* pos = (const int*)d_in[0];
  const float* hs = (const float*)d_in[1];
  const float* wpack = (const float*)d_in[2];
  const float* wo = (const float*)d_in[3];
  float* out = (float*)d_out;
  char* ws = (char*)d_ws;
  u16* hs_b    = (u16*)(ws + 0UL);          // dead after gemm1 -> reused as v_t
  u16* wpack_b = (u16*)(ws + 33554432UL);
  u16* wo_b    = (u16*)(ws + 134217728UL);
  u16* qkv_b   = (u16*)(ws + 167772160UL);
  u16* q_r     = (u16*)(ws + 268435456UL);
  u16* k_r     = (u16*)(ws + 301989888UL);
  u16* attn_b  = (u16*)(ws + 335544320UL);
  u16* v_t     = hs_b;

  cvt_bf16<<<16384, 256, 0, stream>>>(hs, hs_b);
  cvt_bf16<<<49152, 256, 0, stream>>>(wpack, wpack_b);
  cvt_bf16<<<16384, 256, 0, stream>>>(wo, wo_b);
  gemm256<false><<<768, 512, 0, stream>>>(hs_b, wpack_b, qkv_b, 4096, 12288, 4096);
  rope_qk<<<4096, 256, 0, stream>>>(qkv_b, pos, q_r, k_r);
  transpose_v<<<2048, 256, 0, stream>>>(qkv_b, v_t);
  flash_fwd<<<64 * 32, 256, 0, stream>>>(q_r, k_r, v_t, attn_b);
  gemm256<true><<<256, 512, 0, stream>>>(attn_b, wo_b, out, 4096, 4096, 4096);
}